// Round 1
// baseline (437.842 us; speedup 1.0000x reference)
//
#include <hip/hip_runtime.h>

// CorrVolume1DBlock: cv[n,i,h,w] = (1/C) * sum_c x1[n,c,h,w] * x2[n,c,h,w-i],
// zero where w-i < 0.  B=8, C=128, H=128, W=256, i in [0,64].
//
// Strategy: one block per (n,h). Stage the C x W slices of x1 and x2 through
// LDS in c-chunks of 32 (x2 widened by 64 zero-filled left columns to absorb
// the w-i<0 boundary). Each thread register-blocks an 8w x 8i output tile
// (64 fp32 accumulators) -> 6 ds_read_b128 per 64 FMAs, keeping the LDS pipe
// roughly balanced with VALU. Each input slice is fetched from HBM once.

constexpr int B  = 8;
constexpr int C  = 128;
constexpr int H  = 128;
constexpr int W  = 256;
constexpr int NI = 65;              // disparity slices 0..64
constexpr int HW  = H * W;          // 32768
constexpr int CHW = C * HW;         // 4194304
constexpr int KC  = 32;             // c-chunk staged in LDS
constexpr int X2W = 320;            // x2 tile cols: j in [0,320) <-> w' = j-64

__global__ __launch_bounds__(256, 2)
void corr_volume_kernel(const float* __restrict__ x1,
                        const float* __restrict__ x2,
                        float* __restrict__ out) {
    const int h   = blockIdx.x;
    const int n   = blockIdx.y;
    const int tid = threadIdx.x;
    const int wq  = tid & 31;   // 32 w-groups, 8 w each -> covers w 0..255
    const int iq  = tid >> 5;   // 8 i-groups, 8 i each -> covers i 0..63

    __shared__ __align__(16) float x1s[KC][W];    // 32 KB
    __shared__ __align__(16) float x2s[KC][X2W];  // 40 KB

    float acc[8][8];
    #pragma unroll
    for (int il = 0; il < 8; ++il)
        #pragma unroll
        for (int wl = 0; wl < 8; ++wl) acc[il][wl] = 0.0f;
    float acc64[8];   // i == 64 slice, live only for iq == 0 threads
    #pragma unroll
    for (int wl = 0; wl < 8; ++wl) acc64[wl] = 0.0f;

    // x2 LDS window this thread needs: j = w - i + 64, w=8wq+wl, i=8iq+il
    // -> j in [8wq-8iq+57, 8wq-8iq+71]; aligned 16-float window at j0.
    const int j0 = 8 * wq - 8 * iq + 56;   // in [0, 304], 16B-aligned

    const float* x1g = x1 + n * CHW + h * W;
    const float* x2g = x2 + n * CHW + h * W;

    for (int c0 = 0; c0 < C; c0 += KC) {
        // ---- stage x1: KC rows x 64 float4 (flat, rows contiguous) ----
        for (int e = tid; e < KC * (W / 4); e += 256) {
            const int row = e >> 6;
            const int col = e & 63;
            ((float4*)x1s)[e] =
                *(const float4*)(x1g + (c0 + row) * HW + col * 4);
        }
        // ---- stage x2: KC rows x 80 float4, left 16 f4 per row zeroed ----
        for (int e = tid; e < KC * (X2W / 4); e += 256) {
            const int row = e / 80;
            const int col = e - row * 80;
            const int wp  = col * 4 - 64;           // global w'
            float4 v;
            if (wp >= 0) v = *(const float4*)(x2g + (c0 + row) * HW + wp);
            else         v = make_float4(0.f, 0.f, 0.f, 0.f);
            ((float4*)x2s)[e] = v;
        }
        __syncthreads();

        for (int c = 0; c < KC; ++c) {
            const float4* p1 = (const float4*)&x1s[c][wq * 8];
            const float4 a0 = p1[0], a1 = p1[1];
            const float x1r[8] = {a0.x, a0.y, a0.z, a0.w,
                                  a1.x, a1.y, a1.z, a1.w};
            const float4* p2 = (const float4*)&x2s[c][j0];
            const float4 b0 = p2[0], b1 = p2[1], b2 = p2[2], b3 = p2[3];
            const float x2r[16] = {b0.x, b0.y, b0.z, b0.w,
                                   b1.x, b1.y, b1.z, b1.w,
                                   b2.x, b2.y, b2.z, b2.w,
                                   b3.x, b3.y, b3.z, b3.w};
            #pragma unroll
            for (int il = 0; il < 8; ++il)
                #pragma unroll
                for (int wl = 0; wl < 8; ++wl)
                    acc[il][wl] = fmaf(x1r[wl], x2r[wl - il + 8], acc[il][wl]);

            if (iq == 0) {  // i == 64: j = w, i.e. x2s[c][8wq + wl]
                const float4* p3 = (const float4*)&x2s[c][wq * 8];
                const float4 c0v = p3[0], c1v = p3[1];
                const float x2c[8] = {c0v.x, c0v.y, c0v.z, c0v.w,
                                      c1v.x, c1v.y, c1v.z, c1v.w};
                #pragma unroll
                for (int wl = 0; wl < 8; ++wl)
                    acc64[wl] = fmaf(x1r[wl], x2c[wl], acc64[wl]);
            }
        }
        __syncthreads();
    }

    // ---- epilogue: out[n, i, h, w] ----
    const float scale = 1.0f / (float)C;
    float* outg = out + n * (NI * HW) + h * W + wq * 8;
    #pragma unroll
    for (int il = 0; il < 8; ++il) {
        const int i = iq * 8 + il;
        float4 lo = make_float4(acc[il][0] * scale, acc[il][1] * scale,
                                acc[il][2] * scale, acc[il][3] * scale);
        float4 hi = make_float4(acc[il][4] * scale, acc[il][5] * scale,
                                acc[il][6] * scale, acc[il][7] * scale);
        *(float4*)(outg + i * HW)     = lo;
        *(float4*)(outg + i * HW + 4) = hi;
    }
    if (iq == 0) {
        float4 lo = make_float4(acc64[0] * scale, acc64[1] * scale,
                                acc64[2] * scale, acc64[3] * scale);
        float4 hi = make_float4(acc64[4] * scale, acc64[5] * scale,
                                acc64[6] * scale, acc64[7] * scale);
        *(float4*)(outg + 64 * HW)     = lo;
        *(float4*)(outg + 64 * HW + 4) = hi;
    }
}

extern "C" void kernel_launch(void* const* d_in, const int* in_sizes, int n_in,
                              void* d_out, int out_size, void* d_ws, size_t ws_size,
                              hipStream_t stream) {
    const float* x1 = (const float*)d_in[0];
    const float* x2 = (const float*)d_in[1];
    float* out = (float*)d_out;
    dim3 grid(H, B);   // 1024 blocks, one per (n, h)
    corr_volume_kernel<<<grid, 256, 0, stream>>>(x1, x2, out);
}